// Round 5
// baseline (1493.081 us; speedup 1.0000x reference)
//
#include <hip/hip_runtime.h>
#include <math.h>

// ---------- types ----------
typedef __bf16 bf16x8 __attribute__((ext_vector_type(8)));
typedef float fx4 __attribute__((ext_vector_type(4)));
typedef unsigned short u16;
typedef unsigned short u16x8 __attribute__((ext_vector_type(8)));
typedef unsigned int u32;

__device__ __forceinline__ fx4 mfma16(bf16x8 a, bf16x8 b, fx4 c) {
  return __builtin_amdgcn_mfma_f32_16x16x32_bf16(a, b, c, 0, 0, 0);
}
__device__ __forceinline__ u16 f2bf(float f) {  // RNE float->bf16
  u32 u = __float_as_uint(f);
  u += 0x7fffu + ((u >> 16) & 1u);
  return (u16)(u >> 16);
}

// async global->LDS, 16 B per lane. LDS dest is wave-uniform base + lane*16.
// Generic->as(3) via integer truncation (LDS offset lives in low 32 bits).
#define ASYNC16(gsrc, ldst)                                                        \
  __builtin_amdgcn_global_load_lds(                                                \
      (const __attribute__((address_space(1))) unsigned int*)(unsigned long long)(gsrc), \
      (__attribute__((address_space(3))) unsigned int*)(unsigned int)(unsigned long long)(ldst), \
      16, 0, 0)

// ---------- problem constants ----------
#define BB 8
#define SS 2048
#define DD 512
#define HH 8
#define DQ 64
#define DV 512
#define VP 4096

// ---------- workspace layout (bytes) ----------
#define OFF_QP  ((size_t)0)            // 16384x512 bf16 = 16 MB
#define OFF_KP  ((size_t)16777216)     // 16384x512 bf16 = 16 MB
#define OFF_WQT ((size_t)33554432)
#define OFF_WKT ((size_t)34078720)
#define OFF_WVT ((size_t)34603008)
#define OFF_WOT ((size_t)38797312)
#define OFF_MPT ((size_t)42991616)     // transposed bitmask, 4 MB
#define OFF_VT  ((size_t)76546048)     // 8*4096*2048 bf16 = 128 MB
#define OFF_XB  ((size_t)210763776)    // 16384x4096 bf16 = 134 MB

// ---------- weight transpose + bf16 convert ----------
__global__ __launch_bounds__(256) void transpose_w(const float* __restrict__ W,
                                                   u16* __restrict__ Wt,
                                                   int K, int N) {
  __shared__ float t[32][33];
  const int n0 = blockIdx.x * 32, k0 = blockIdx.y * 32;
  const int tx = threadIdx.x & 31, ty = threadIdx.x >> 5;
#pragma unroll
  for (int i = 0; i < 32; i += 8)
    t[ty + i][tx] = W[(size_t)(k0 + ty + i) * N + n0 + tx];
  __syncthreads();
#pragma unroll
  for (int i = 0; i < 32; i += 8)
    Wt[(size_t)(n0 + ty + i) * K + k0 + tx] = f2bf(t[tx][ty + i]);
}

// ---------- transposed mask pack: mp_t[b][roww][col], bit = row&31 ----------
__global__ __launch_bounds__(256) void pack_mask_t(const int* __restrict__ mask,
                                                   u32* __restrict__ mpt) {
  __shared__ int tile[64 * 260];
  const int b = blockIdx.z, row0 = blockIdx.y * 64, col0 = blockIdx.x * 256;
  const int tid = threadIdx.x;
#pragma unroll
  for (int j = 0; j < 16; ++j) {
    int idx = j * 1024 + tid * 4;
    int row = idx >> 8, col = idx & 255;
    int4 v = *(const int4*)&mask[(size_t)(b * SS + row0 + row) * SS + col0 + col];
    *(int4*)&tile[row * 260 + col] = v;
  }
  __syncthreads();
  const int col = tid;
  u32 w0 = 0, w1 = 0;
#pragma unroll
  for (int r = 0; r < 32; ++r) {
    if (tile[r * 260 + col] != 0) w0 |= (1u << r);
    if (tile[(r + 32) * 260 + col] != 0) w1 |= (1u << r);
  }
  size_t base = ((size_t)(b * 64) + (row0 >> 5)) * 2048 + col0 + col;
  mpt[base] = w0;
  mpt[base + 2048] = w1;
}

// ---------- GEMM: C[M,N] = A[M,K] @ Bt[N,K]^T (128x128 tile, async staging) ----
template <int AFP32, int EPI>
__global__ __launch_bounds__(256) void gemm_bt(const void* __restrict__ Ap,
                                               const u16* __restrict__ Bt,
                                               void* __restrict__ Cp,
                                               int M, int N, int K,
                                               const float* __restrict__ bias,
                                               float scale) {
  __shared__ union {
    struct { u16 As[128 * 32]; u16 Bs[128 * 32]; } s;
    u16 T[4][64 * 68];
  } sm;
  const int tid = threadIdx.x;
  const int lane = tid & 63, w = tid >> 6;
  const int lhi = lane >> 4, llo = lane & 15;
  const int wm = w >> 1, wn = w & 1;
  const int m0 = blockIdx.y * 128, n0 = blockIdx.x * 128;

  fx4 acc[4][4];
#pragma unroll
  for (int i = 0; i < 4; ++i)
#pragma unroll
    for (int j = 0; j < 4; ++j) acc[i][j] = (fx4){0.f, 0.f, 0.f, 0.f};

  for (int k0 = 0; k0 < K; k0 += 32) {
    if (AFP32) {
      const float* A = (const float*)Ap;
      const int row = tid >> 1, co = (tid & 1) * 16;
      const float* src = A + (size_t)(m0 + row) * K + k0 + co;
      float4 v0 = *(const float4*)(src + 0);
      float4 v1 = *(const float4*)(src + 4);
      float4 v2 = *(const float4*)(src + 8);
      float4 v3 = *(const float4*)(src + 12);
      u16x8 p0 = {f2bf(v0.x), f2bf(v0.y), f2bf(v0.z), f2bf(v0.w),
                  f2bf(v1.x), f2bf(v1.y), f2bf(v1.z), f2bf(v1.w)};
      u16x8 p1 = {f2bf(v2.x), f2bf(v2.y), f2bf(v2.z), f2bf(v2.w),
                  f2bf(v3.x), f2bf(v3.y), f2bf(v3.z), f2bf(v3.w)};
      *(u16x8*)&sm.s.As[row * 32 + co] = p0;
      *(u16x8*)&sm.s.As[row * 32 + co + 8] = p1;
    } else {
      const u16* A = (const u16*)Ap;
#pragma unroll
      for (int j = 0; j < 2; ++j) {
        int cc = j * 256 + tid;
        int row = cc >> 2, c8 = (cc & 3) * 8;
        ASYNC16(&A[(size_t)(m0 + row) * K + k0 + c8],
                (char*)sm.s.As + j * 4096 + w * 1024);
      }
    }
#pragma unroll
    for (int j = 0; j < 2; ++j) {
      int cc = j * 256 + tid;
      int row = cc >> 2, c8 = (cc & 3) * 8;
      ASYNC16(&Bt[(size_t)(n0 + row) * K + k0 + c8],
              (char*)sm.s.Bs + j * 4096 + w * 1024);
    }
    __syncthreads();
    bf16x8 af[4], bfv[4];
#pragma unroll
    for (int mi = 0; mi < 4; ++mi)
      af[mi] = *(const bf16x8*)&sm.s.As[(wm * 64 + mi * 16 + llo) * 32 + lhi * 8];
#pragma unroll
    for (int ni = 0; ni < 4; ++ni)
      bfv[ni] = *(const bf16x8*)&sm.s.Bs[(wn * 64 + ni * 16 + llo) * 32 + lhi * 8];
#pragma unroll
    for (int mi = 0; mi < 4; ++mi)
#pragma unroll
      for (int ni = 0; ni < 4; ++ni)
        acc[mi][ni] = mfma16(af[mi], bfv[ni], acc[mi][ni]);
    __syncthreads();
  }

  const int rbase = m0 + wm * 64, cbase = n0 + wn * 64;
  if (EPI == 0) {
    u16* C = (u16*)Cp;
#pragma unroll
    for (int mi = 0; mi < 4; ++mi) {
      int r0 = rbase + mi * 16 + lhi * 4;
#pragma unroll
      for (int ni = 0; ni < 4; ++ni) {
        int c = cbase + ni * 16 + llo;
#pragma unroll
        for (int r = 0; r < 4; ++r)
          C[(size_t)(r0 + r) * N + c] = f2bf(acc[mi][ni][r] * scale);
      }
    }
  } else if (EPI == 1) {
    // Vt[b][n][s]: wave-private LDS transpose, then 128B-contiguous stores.
    u16* Tw = &sm.T[w][0];
#pragma unroll
    for (int mi = 0; mi < 4; ++mi)
#pragma unroll
      for (int ni = 0; ni < 4; ++ni) {
        ushort4 pk;
        pk.x = f2bf(acc[mi][ni][0]);
        pk.y = f2bf(acc[mi][ni][1]);
        pk.z = f2bf(acc[mi][ni][2]);
        pk.w = f2bf(acc[mi][ni][3]);
        *(ushort4*)&Tw[(ni * 16 + llo) * 68 + mi * 16 + lhi * 4] = pk;
      }
    u16* VtC = (u16*)Cp;
    const int bsel = rbase >> 11;
    const int sb = rbase & 2047;
    u16* dst = VtC + ((size_t)(bsel * VP + cbase + lane)) * SS + sb;
#pragma unroll
    for (int j = 0; j < 8; ++j) {
      u16x8 vv = *(u16x8*)&Tw[lane * 68 + j * 8];
      *(u16x8*)&dst[j * 8] = vv;
    }
  } else {
    float* C = (float*)Cp;
#pragma unroll
    for (int ni = 0; ni < 4; ++ni) {
      int c = cbase + ni * 16 + llo;
      float bv = bias[c];
#pragma unroll
      for (int mi = 0; mi < 4; ++mi) {
        int r0 = rbase + mi * 16 + lhi * 4;
#pragma unroll
        for (int r = 0; r < 4; ++r)
          C[(size_t)(r0 + r) * N + c] = acc[mi][ni][r] + bv;
      }
    }
  }
}

// ---------- flash attention: one barrier/iter, in-register mask+exp ----------
// BM=64, BN=64, 4 waves. Wave w: S cols [w*16,w*16+16); PV dv slice
// [w*128,(w+1)*128). S stays in C-layout regs; P written straight to Psm
// (ping-pong). l = per-lane partials, reduced once at end.
#define PS_ 68
#define QS_ 72
__global__ __launch_bounds__(256, 2) void attn(const u16* __restrict__ Qp,
                                               const u16* __restrict__ Kp,
                                               const u16* __restrict__ Vt,
                                               const u32* __restrict__ mpt,
                                               u16* __restrict__ Xb) {
  const int lin = blockIdx.x;
  const int xcd = lin & 7, idx = lin >> 3;
  const int bh = xcd * 8 + (idx >> 5);
  const int qt = idx & 31;
  const int b = bh & 7, h = bh >> 3;
  const int m0 = qt * 64;
  const int tid = threadIdx.x, w = tid >> 6, lane = tid & 63;
  const int lhi = lane >> 4, llo = lane & 15;

  __shared__ u16 Qs[64 * QS_];
  __shared__ u16 Psm[2][64 * PS_];
  __shared__ float sm_lp[4][64];
  __shared__ float sm_l[64];

  // stage Q tile (64x64 bf16)
  {
    int row = tid >> 2, c0 = (tid & 3) * 16;
    const u16* src = &Qp[(size_t)(b * SS + m0 + row) * 512 + h * DQ + c0];
    *(uint4*)&Qs[row * QS_ + c0] = *(const uint4*)(src);
    *(uint4*)&Qs[row * QS_ + c0 + 8] = *(const uint4*)(src + 8);
  }

  fx4 acc[4][8];
#pragma unroll
  for (int mt = 0; mt < 4; ++mt)
#pragma unroll
    for (int nt = 0; nt < 8; ++nt) acc[mt][nt] = (fx4){0.f, 0.f, 0.f, 0.f};
  fx4 lac[4];
#pragma unroll
  for (int mt = 0; mt < 4; ++mt) lac[mt] = (fx4){0.f, 0.f, 0.f, 0.f};

  const int colw = w * 16 + llo;
  const size_t kbase = (size_t)(b * SS) * 512 + h * DQ + lhi * 8;
  const u32* mpt_b = mpt + (size_t)(b * 64 + (m0 >> 5)) * 2048 + colw;
  const size_t vbase = (size_t)(b * VP + h * DV + w * 128) * SS + lhi * 8;

  // first-iter prefetch
  bf16x8 kf0 = *(const bf16x8*)&Kp[kbase + (size_t)colw * 512];
  bf16x8 kf1 = *(const bf16x8*)&Kp[kbase + (size_t)colw * 512 + 32];
  u32 mw0 = mpt_b[0], mw1 = mpt_b[2048];

  __syncthreads();  // Qs ready

  for (int n0 = 0; n0 < SS; n0 += 64) {
    const int cur = (n0 >> 6) & 1;
    u16* P = &Psm[cur][0];
    // ---- S = Q K^T, mask+exp in C-layout regs, write P ----
#pragma unroll
    for (int mt = 0; mt < 4; ++mt) {
      bf16x8 qa0 = *(const bf16x8*)&Qs[(mt * 16 + llo) * QS_ + lhi * 8];
      bf16x8 qa1 = *(const bf16x8*)&Qs[(mt * 16 + llo) * QS_ + 32 + lhi * 8];
      fx4 s = (fx4){0.f, 0.f, 0.f, 0.f};
      s = mfma16(qa0, kf0, s);
      s = mfma16(qa1, kf1, s);
      const u32 mwv = (mt < 2) ? mw0 : mw1;
      const int bb = (mt & 1) * 16 + lhi * 4;
#pragma unroll
      for (int r = 0; r < 4; ++r) {
        float p = ((mwv >> (bb + r)) & 1u) ? __expf(s[r]) : 0.f;
        lac[mt][r] += p;
        P[(mt * 16 + lhi * 4 + r) * PS_ + colw] = f2bf(p);
      }
    }
    // ---- prefetch next iter's K + mask, this iter's first V (pre-barrier) ----
    const int n1 = (n0 + 64) & (SS - 1);
    kf0 = *(const bf16x8*)&Kp[kbase + (size_t)(n1 + colw) * 512];
    kf1 = *(const bf16x8*)&Kp[kbase + (size_t)(n1 + colw) * 512 + 32];
    mw0 = mpt_b[n1];
    mw1 = mpt_b[n1 + 2048];
    bf16x8 v00 = *(const bf16x8*)&Vt[vbase + (size_t)llo * SS + n0];
    bf16x8 v01 = *(const bf16x8*)&Vt[vbase + (size_t)llo * SS + n0 + 32];
    __syncthreads();

    // ---- O += P @ V ----
    bf16x8 pf[4][2];
#pragma unroll
    for (int mt = 0; mt < 4; ++mt)
#pragma unroll
      for (int kk = 0; kk < 2; ++kk)
        pf[mt][kk] = *(const bf16x8*)&P[(mt * 16 + llo) * PS_ + kk * 32 + lhi * 8];
#pragma unroll
    for (int nt = 0; nt < 8; ++nt) {
      bf16x8 vf0, vf1;
      if (nt == 0) { vf0 = v00; vf1 = v01; }
      else {
        vf0 = *(const bf16x8*)&Vt[vbase + (size_t)(nt * 16 + llo) * SS + n0];
        vf1 = *(const bf16x8*)&Vt[vbase + (size_t)(nt * 16 + llo) * SS + n0 + 32];
      }
#pragma unroll
      for (int mt = 0; mt < 4; ++mt) {
        fx4 a = acc[mt][nt];
        a = mfma16(pf[mt][0], vf0, a);
        a = mfma16(pf[mt][1], vf1, a);
        acc[mt][nt] = a;
      }
    }
  }

  // ---- l: reduce per-lane partials across the 16 llo lanes, sum over waves ----
#pragma unroll
  for (int mt = 0; mt < 4; ++mt)
#pragma unroll
    for (int r = 0; r < 4; ++r) {
      float v = lac[mt][r];
      v += __shfl_xor(v, 1); v += __shfl_xor(v, 2);
      v += __shfl_xor(v, 4); v += __shfl_xor(v, 8);
      lac[mt][r] = v;
    }
  if (llo == 0) {
#pragma unroll
    for (int mt = 0; mt < 4; ++mt)
#pragma unroll
      for (int r = 0; r < 4; ++r)
        sm_lp[w][mt * 16 + lhi * 4 + r] = lac[mt][r];
  }
  __syncthreads();
  if (tid < 64)
    sm_l[tid] = sm_lp[0][tid] + sm_lp[1][tid] + sm_lp[2][tid] + sm_lp[3][tid];
  __syncthreads();

  float linv[4][4];
#pragma unroll
  for (int mt = 0; mt < 4; ++mt)
#pragma unroll
    for (int r = 0; r < 4; ++r) linv[mt][r] = 1.0f / sm_l[mt * 16 + lhi * 4 + r];

  // ---- epilogue: normalize, restage through LDS (alias Psm), coalesced store ----
  u16* Xs = &Psm[0][0];  // 16 rows x 520 = 16640 B <= 17408 B
  const int er = tid >> 4, ec = (tid & 15) * 32;
#pragma unroll
  for (int mt = 0; mt < 4; ++mt) {
#pragma unroll
    for (int nt = 0; nt < 8; ++nt)
#pragma unroll
      for (int r = 0; r < 4; ++r)
        Xs[(lhi * 4 + r) * 520 + w * 128 + nt * 16 + llo] =
            f2bf(acc[mt][nt][r] * linv[mt][r]);
    __syncthreads();
    {
      const u16* src = Xs + er * 520 + ec;
      u16* dst = Xb + (size_t)((h * 8 + b) * SS + m0 + mt * 16 + er) * 512 + ec;
      uint4 a0 = *(const uint4*)(src + 0);
      uint4 a1 = *(const uint4*)(src + 8);
      uint4 a2 = *(const uint4*)(src + 16);
      uint4 a3 = *(const uint4*)(src + 24);
      *(uint4*)(dst + 0) = a0;
      *(uint4*)(dst + 8) = a1;
      *(uint4*)(dst + 16) = a2;
      *(uint4*)(dst + 24) = a3;
    }
    __syncthreads();
  }
}

// ---------- launcher ----------
extern "C" void kernel_launch(void* const* d_in, const int* in_sizes, int n_in,
                              void* d_out, int out_size, void* d_ws, size_t ws_size,
                              hipStream_t stream) {
  (void)in_sizes; (void)n_in; (void)out_size; (void)ws_size;
  const float* q_in = (const float*)d_in[0];
  const float* k_in = (const float*)d_in[1];
  const float* v_in = (const float*)d_in[2];
  const float* W_q  = (const float*)d_in[3];
  const float* W_k  = (const float*)d_in[4];
  const float* W_v  = (const float*)d_in[5];
  const float* W_o  = (const float*)d_in[6];
  const float* b_o  = (const float*)d_in[7];
  const int*   mask = (const int*)d_in[8];

  char* ws = (char*)d_ws;
  u16* Qp   = (u16*)(ws + OFF_QP);
  u16* Kp   = (u16*)(ws + OFF_KP);
  u16* Wqt  = (u16*)(ws + OFF_WQT);
  u16* Wkt  = (u16*)(ws + OFF_WKT);
  u16* Wvt  = (u16*)(ws + OFF_WVT);
  u16* Wot  = (u16*)(ws + OFF_WOT);
  u32* mpt  = (u32*)(ws + OFF_MPT);
  u16* Vt   = (u16*)(ws + OFF_VT);
  u16* Xb   = (u16*)(ws + OFF_XB);

  transpose_w<<<dim3(16, 16), 256, 0, stream>>>(W_q, Wqt, 512, 512);
  transpose_w<<<dim3(16, 16), 256, 0, stream>>>(W_k, Wkt, 512, 512);
  transpose_w<<<dim3(128, 16), 256, 0, stream>>>(W_v, Wvt, 512, 4096);
  transpose_w<<<dim3(16, 128), 256, 0, stream>>>(W_o, Wot, 4096, 512);

  pack_mask_t<<<dim3(8, 32, 8), 256, 0, stream>>>(mask, mpt);

  gemm_bt<1, 0><<<dim3(4, 128), 256, 0, stream>>>(q_in, Wqt, Qp, 16384, 512, 512, nullptr, 0.125f);
  gemm_bt<1, 0><<<dim3(4, 128), 256, 0, stream>>>(k_in, Wkt, Kp, 16384, 512, 512, nullptr, 1.0f);
  gemm_bt<1, 1><<<dim3(32, 128), 256, 0, stream>>>(v_in, Wvt, Vt, 16384, 4096, 512, nullptr, 1.0f);

  attn<<<dim3(2048), 256, 0, stream>>>(Qp, Kp, Vt, mpt, Xb);

  gemm_bt<0, 2><<<dim3(4, 128), 256, 0, stream>>>(Xb, Wot, d_out, 16384, 512, 4096, b_o, 1.0f);
}